// Round 5
// baseline (271.992 us; speedup 1.0000x reference)
//
#include <hip/hip_runtime.h>

typedef unsigned short u16;
using bf16x8 = __attribute__((ext_vector_type(8))) short;   // 8 bf16 (4 VGPRs)
using f32x4  = __attribute__((ext_vector_type(4))) float;   // 4 fp32

__device__ __forceinline__ u16 f2b(float f) {
    __bf16 h = (__bf16)f;
    return __builtin_bit_cast(unsigned short, h);
}
__device__ __forceinline__ float b2f(u16 u) {
    return (float)__builtin_bit_cast(__bf16, u);
}
__device__ __forceinline__ void gload16(const u16* g, const u16* l) {
    __builtin_amdgcn_global_load_lds(
        (const __attribute__((address_space(1))) unsigned int*)g,
        (__attribute__((address_space(3))) unsigned int*)l, 16, 0, 0);
}

// C = A * B^T (A: MxK rm, B: NxK rm), bf16 in, fp32 MFMA accum.
// 4-phase/tile counted-vmcnt pipeline on R1's PROVEN zero-conflict LDS geometry:
// rows of 64 bf16 (128B stride), 16B chunks XOR-swizzled by (row&7) on BOTH sides
// (pre-swizzled global source + XOR'd ds_read). BM=256, BN=NBLK*64, BK=64.
// 8 waves (2M x 4N); per-wave 128 x NBLK*16. LDS: 2 parity slots per operand.
// Issue: A(t+1) at p1/p2 (slot s1 A read-free since p4(t-1) barrier);
//        B(t+2) at p4 (slot s  B read-free after p3 barrier).
// Boundary: vmcnt(BROUND) — B(t+2) stays in flight; never drain to 0 mid-loop.
// MODE 0: C_bf16 = acc + bias[col]
// MODE 2: P_bf16 = exp2(acc*wk[col]); atomicAdd(rowsum[row], sum of bf16-rounded P)
// MODE 3: C_f32  = acc / rowsum[row]
template<int MODE, int NBLK>
__global__ __launch_bounds__(512, 2)
void gemm8(const u16* __restrict__ A, const u16* __restrict__ B,
           void* __restrict__ Cv, const float* __restrict__ aux,
           float* __restrict__ rowsum,
           int K, int lda, int ldb, int ldc,
           long strA, long strB, long strC, long strAux, long strRS)
{
    constexpr int BR = NBLK * 64;                  // B tile rows (= C cols per block)
    constexpr int BROUND = BR / 64;                // gload16 rounds for B (4 or 2)
    __shared__ __align__(16) u16 sA[2][256 * 64];
    __shared__ __align__(16) u16 sB[2][BR * 64];

    const int tid  = threadIdx.x;
    const int lane = tid & 63;
    const int wave = tid >> 6;                     // 0..7
    const int wm = wave >> 2, wn = wave & 3;       // 2M x 4N
    const int l16 = lane & 15, qld = lane >> 4;

    // XCD-chunked bijective swizzle (nxy % 8 == 0 for all our grids); for the
    // scores grid (gx=8) this puts one bx column per XCD -> shared K panel in L2.
    const int gx = gridDim.x, gy = gridDim.y;
    const int nxy = gx * gy;
    int li = blockIdx.y * gx + blockIdx.x;
    li = (li & 7) * (nxy >> 3) + (li >> 3);
    const int bx = li % gx, by = li / gx;
    const int bn0 = bx * BR, bm0 = by * 256;
    const long z = blockIdx.z;

    const u16* Ab = A + z * strA + (long)bm0 * lda;
    const u16* Bb = B + z * strB + (long)bn0 * ldb;
    const float* auxp = aux + z * strAux;

    // staging: chunk ci = round*512 + tid; row = ci>>3, phys chunk c = ci&7 holds
    // global chunk c ^ (row&7). LDS linear (byte off = ci*16 = row*128 + c*16).
    const u16* srcA[4];
    const u16* srcB[BROUND];
#pragma unroll
    for (int i = 0; i < 4; ++i) {
        const int ci = i * 512 + tid, row = ci >> 3, c = ci & 7;
        srcA[i] = Ab + (long)row * lda + (c ^ (row & 7)) * 8;
    }
#pragma unroll
    for (int i = 0; i < BROUND; ++i) {
        const int ci = i * 512 + tid, row = ci >> 3, c = ci & 7;
        srcB[i] = Bb + (long)row * ldb + (c ^ (row & 7)) * 8;
    }
    const int wch = (tid & ~63) * 8;               // wave-uniform LDS offset (u16)

#define STAGE_A2(sl, kc, i0) do { \
    gload16(srcA[i0] + (kc),     &sA[sl][(i0) * 4096 + wch]); \
    gload16(srcA[i0 + 1] + (kc), &sA[sl][(i0 + 1) * 4096 + wch]); } while (0)
#define STAGE_B(sl, kc) do { \
    _Pragma("unroll") \
    for (int i = 0; i < BROUND; ++i) \
        gload16(srcB[i] + (kc), &sB[sl][i * 4096 + wch]); } while (0)

    f32x4 acc[8][NBLK] = {};
    const int NT = K >> 6;

    // R1's proven conflict-free read expression
    auto rdA = [&](int s, int mf, int kh) -> bf16x8 {
        const int row = wm * 128 + mf * 16 + l16;
        int byte_off = row * 128 + (kh * 32 + qld * 8) * 2;
        byte_off ^= (row & 7) << 4;
        return *(const bf16x8*)((const char*)&sA[s][0] + byte_off);
    };
    auto rdB = [&](int s, int n, int kh) -> bf16x8 {
        const int row = wn * (NBLK * 16) + n * 16 + l16;
        int byte_off = row * 128 + (kh * 32 + qld * 8) * 2;
        byte_off ^= (row & 7) << 4;
        return *(const bf16x8*)((const char*)&sB[s][0] + byte_off);
    };

#define MFMA_HALF(base) do { \
    __builtin_amdgcn_s_setprio(1); \
    _Pragma("unroll") \
    for (int j = 0; j < 4; ++j) \
        _Pragma("unroll") \
        for (int n = 0; n < NBLK; ++n) \
            acc[(base) + j][n] = __builtin_amdgcn_mfma_f32_16x16x32_bf16(afr[j], bfr[n], acc[(base) + j][n], 0, 0, 0); \
    __builtin_amdgcn_s_setprio(0); } while (0)

#define BAR()   asm volatile("s_barrier" ::: "memory")
#define LGKM0() do { asm volatile("s_waitcnt lgkmcnt(0)" ::: "memory"); \
                     __builtin_amdgcn_sched_barrier(0); } while (0)

    // prologue: tile0 (slot0) + B(1) (slot1). vmcnt(BROUND): drain tile0, B(1) flies.
    STAGE_A2(0, 0, 0); STAGE_A2(0, 0, 2);
    STAGE_B(0, 0);
    STAGE_B(1, 64);
    asm volatile("s_waitcnt vmcnt(%0)" :: "i"(BROUND) : "memory");
    __builtin_amdgcn_sched_barrier(0);
    BAR();

    for (int t = 0; t < NT; ++t) {
        const int s = t & 1, s1 = s ^ 1;
        bf16x8 afr[4], bfr[NBLK];

        // -------- p1: qm0,kh0; issue A(t+1) rounds 0-1 --------
#pragma unroll
        for (int j = 0; j < 4; ++j) afr[j] = rdA(s, j, 0);
#pragma unroll
        for (int n = 0; n < NBLK; ++n) bfr[n] = rdB(s, n, 0);
        if (t + 1 < NT) STAGE_A2(s1, (t + 1) * 64, 0);
        BAR(); LGKM0();
        MFMA_HALF(0);
        BAR();

        // -------- p2: qm1,kh0; issue A(t+1) rounds 2-3 --------
#pragma unroll
        for (int j = 0; j < 4; ++j) afr[j] = rdA(s, 4 + j, 0);
        if (t + 1 < NT) STAGE_A2(s1, (t + 1) * 64, 2);
        BAR(); LGKM0();
        MFMA_HALF(4);
        BAR();

        // -------- p3: qm0,kh1 --------
#pragma unroll
        for (int j = 0; j < 4; ++j) afr[j] = rdA(s, j, 1);
#pragma unroll
        for (int n = 0; n < NBLK; ++n) bfr[n] = rdB(s, n, 1);
        BAR(); LGKM0();
        MFMA_HALF(0);
        BAR();

        // -------- p4: qm1,kh1; issue B(t+2) (B[s] read-free after p3 barrier) --------
#pragma unroll
        for (int j = 0; j < 4; ++j) afr[j] = rdA(s, 4 + j, 1);
        if (t + 2 < NT) STAGE_B(s, (t + 2) * 64);
        BAR(); LGKM0();
        MFMA_HALF(4);
        if (t + 2 < NT) asm volatile("s_waitcnt vmcnt(%0)" :: "i"(BROUND) : "memory");
        else            asm volatile("s_waitcnt vmcnt(0)" ::: "memory");
        __builtin_amdgcn_sched_barrier(0);
        BAR();
    }
#undef STAGE_A2
#undef STAGE_B
#undef MFMA_HALF
#undef BAR
#undef LGKM0

    // C/D layout: col = lane&15, row = (lane>>4)*4 + reg
    const int rg = lane >> 4;
    const int orow0 = bm0 + wm * 128;
    const int ocol0 = bn0 + wn * (NBLK * 16);

    if constexpr (MODE == 0) {
        u16* Co = (u16*)Cv + z * strC;
        float bias[NBLK];
#pragma unroll
        for (int n = 0; n < NBLK; ++n) bias[n] = auxp[ocol0 + n * 16 + l16];
#pragma unroll
        for (int mf = 0; mf < 8; ++mf)
#pragma unroll
            for (int n = 0; n < NBLK; ++n) {
                const int col = ocol0 + n * 16 + l16;
#pragma unroll
                for (int r = 0; r < 4; ++r) {
                    const int row = orow0 + mf * 16 + rg * 4 + r;
                    Co[(long)row * ldc + col] = f2b(acc[mf][n][r] + bias[n]);
                }
            }
    } else if constexpr (MODE == 2) {
        u16* Co = (u16*)Cv + z * strC;
        float* rsp = rowsum + z * strRS;
        float wkn[NBLK];
#pragma unroll
        for (int n = 0; n < NBLK; ++n) wkn[n] = auxp[ocol0 + n * 16 + l16];
#pragma unroll
        for (int mf = 0; mf < 8; ++mf)
#pragma unroll
            for (int r = 0; r < 4; ++r) {
                const int row = orow0 + mf * 16 + rg * 4 + r;
                float partial = 0.f;
#pragma unroll
                for (int n = 0; n < NBLK; ++n) {
                    const int col = ocol0 + n * 16 + l16;
                    const float p = exp2f(acc[mf][n][r] * wkn[n]);
                    const u16 pb = f2b(p);
                    Co[(long)row * ldc + col] = pb;
                    partial += b2f(pb);   // denominator from bf16-rounded P
                }
                partial += __shfl_xor(partial, 1);
                partial += __shfl_xor(partial, 2);
                partial += __shfl_xor(partial, 4);
                partial += __shfl_xor(partial, 8);
                if (l16 == 0) atomicAdd(&rsp[row], partial);
            }
    } else {  // MODE 3
        float* Co = (float*)Cv + z * strC;
#pragma unroll
        for (int mf = 0; mf < 8; ++mf)
#pragma unroll
            for (int r = 0; r < 4; ++r) {
                const int row = orow0 + mf * 16 + rg * 4 + r;
                const float inv = 1.0f / auxp[row];
#pragma unroll
                for (int n = 0; n < NBLK; ++n) {
                    const int col = ocol0 + n * 16 + l16;
                    Co[(long)row * ldc + col] = acc[mf][n][r] * inv;
                }
            }
    }
}

__global__ void cvt_bf16(const float* __restrict__ in, u16* __restrict__ out, int n4) {
    const int i = blockIdx.x * 256 + threadIdx.x;
    if (i >= n4) return;
    const float4 f = ((const float4*)in)[i];
    ushort4 o;
    o.x = f2b(f.x); o.y = f2b(f.y); o.z = f2b(f.z); o.w = f2b(f.w);
    ((ushort4*)out)[i] = o;
}

__global__ void wk_kernel(const float* __restrict__ eig, float* __restrict__ wk, int n) {
    const int i = blockIdx.x * 256 + threadIdx.x;
    if (i >= n) return;
    const float s = 1.0f / (1.0f + expf(-eig[i]));
    wk[i] = s * (float)(1.4426950408889634 / 22.627416997969522);  // log2(e)/sqrt(512)
}

// V slice of qkvC [16384][1536] (cols 1024..1535) -> Vt [8][512][2048] bf16
__global__ __launch_bounds__(256)
void transpose_v(const u16* __restrict__ Vq, u16* __restrict__ Vt) {
    __shared__ u16 t[64][65];
    const int tid = threadIdx.x;
    const int d0  = blockIdx.x * 64;
    const int bs0 = blockIdx.y * 64;
#pragma unroll
    for (int i = 0; i < 16; ++i) {
        const int idx = i * 256 + tid;
        const int r = idx >> 6, c = idx & 63;
        t[r][c] = Vq[(long)(bs0 + r) * 1536 + d0 + c];
    }
    __syncthreads();
    const long b = bs0 >> 11;
    const int s0 = bs0 & 2047;
#pragma unroll
    for (int i = 0; i < 16; ++i) {
        const int idx = i * 256 + tid;
        const int dch = idx >> 6, ss = idx & 63;
        Vt[(b * 512 + d0 + dch) * 2048 + s0 + ss] = t[ss][dch];
    }
}

extern "C" void kernel_launch(void* const* d_in, const int* in_sizes, int n_in,
                              void* d_out, int out_size, void* d_ws, size_t ws_size,
                              hipStream_t stream) {
    const float* x  = (const float*)d_in[0];
    const float* ev = (const float*)d_in[1];
    const float* Wq = (const float*)d_in[2];
    const float* bq = (const float*)d_in[3];
    const float* Wk = (const float*)d_in[4];
    const float* bk = (const float*)d_in[5];
    const float* Wv = (const float*)d_in[6];
    const float* bv = (const float*)d_in[7];
    float* out = (float*)d_out;

    char* ws = (char*)d_ws;
    u16*   P      = (u16*)(ws);                      // 64 MB  P bf16 [8][2048][2048]
    u16*   xb     = (u16*)(ws + (64ul << 20));       // 16 MB  x bf16 [16384][512]
    u16*   qkvC   = (u16*)(ws + (80ul << 20));       // 48 MB  [16384][1536] = Q|K|V
    u16*   Vt     = (u16*)(ws + (128ul << 20));      // 16 MB  V^T bf16 [8][512][2048]
    u16*   Wb     = (u16*)(ws + (144ul << 20));      // 1.5 MB Wq|Wk|Wv bf16 [1536][512]
    float* biasb  = (float*)(ws + (146ul << 20));    // 6 KB   concat bias [1536]
    float* wk     = (float*)(ws + (146ul << 20) + 65536);   // 64 KB
    float* rowsum = (float*)(ws + (146ul << 20) + 131072);  // 64 KB

    cvt_bf16<<<dim3(8192), dim3(256), 0, stream>>>(x, xb, 2097152);
    cvt_bf16<<<dim3(256),  dim3(256), 0, stream>>>(Wq, Wb,          65536);
    cvt_bf16<<<dim3(256),  dim3(256), 0, stream>>>(Wk, Wb + 262144, 65536);
    cvt_bf16<<<dim3(256),  dim3(256), 0, stream>>>(Wv, Wb + 524288, 65536);
    hipMemcpyAsync(biasb,        bq, 512 * 4, hipMemcpyDeviceToDevice, stream);
    hipMemcpyAsync(biasb + 512,  bk, 512 * 4, hipMemcpyDeviceToDevice, stream);
    hipMemcpyAsync(biasb + 1024, bv, 512 * 4, hipMemcpyDeviceToDevice, stream);
    wk_kernel<<<dim3(64), dim3(256), 0, stream>>>(ev, wk, 16384);
    hipMemsetAsync(rowsum, 0, 65536, stream);

    // QKV projection: M=16384, N=1536 (concat), K=512
    gemm8<0, 2><<<dim3(12, 64, 1), dim3(512), 0, stream>>>(
        xb, Wb, qkvC, biasb, nullptr,
        512, 512, 512, 1536,
        0L, 0L, 0L, 0L, 0L);

    transpose_v<<<dim3(8, 256), dim3(256), 0, stream>>>(qkvC + 1024, Vt);

    // scores + exp: per batch, M=N=2048, K=512
    gemm8<2, 4><<<dim3(8, 8, 8), dim3(512), 0, stream>>>(
        qkvC, qkvC + 512, P, wk, rowsum,
        512, 1536, 1536, 2048,
        3145728L, 3145728L, 4194304L, 2048L, 2048L);

    // PV: per batch, M=2048, N=512, K=2048
    gemm8<3, 2><<<dim3(4, 8, 8), dim3(512), 0, stream>>>(
        P, Vt, out, rowsum, nullptr,
        2048, 2048, 2048, 512,
        4194304L, 1048576L, 1048576L, 2048L, 0L);
}